// Round 5
// baseline (1017.286 us; speedup 1.0000x reference)
//
#include <hip/hip_runtime.h>
#include <math.h>

#define SEQ 192
#define NTOK 24576      // 128*192
#define EPS 1e-5f

typedef __bf16 bf16x8 __attribute__((ext_vector_type(8)));
typedef __bf16 bf16x4 __attribute__((ext_vector_type(4)));
typedef float  f32x4  __attribute__((ext_vector_type(4)));

__device__ __forceinline__ void load_lds16(const __bf16* g, __bf16* l) {
    __builtin_amdgcn_global_load_lds(
        (const __attribute__((address_space(1))) uint32_t*)g,
        (__attribute__((address_space(3))) uint32_t*)l, 16, 0, 0);
}

// tanh-form GELU via sigmoid: x*sigmoid(1.5958*(x+0.044715 x^3))
__device__ __forceinline__ float gelu_f(float x) {
    float z = 1.5957691216057308f * x * fmaf(0.044715f, x*x, 1.f);
    float e = __expf(-z);
    return x * __builtin_amdgcn_rcpf(1.f + e);
}

// ---------------- f32 -> bf16 bulk convert (weights) ----------------
__global__ __launch_bounds__(256) void cvt_k(const float* __restrict__ x, __bf16* __restrict__ y)
{
    int i = blockIdx.x * 256 + threadIdx.x;
    f32x4 v = ((const f32x4*)x)[i];
    bf16x4 o;
    o[0]=(__bf16)v[0]; o[1]=(__bf16)v[1]; o[2]=(__bf16)v[2]; o[3]=(__bf16)v[3];
    ((bf16x4*)y)[i] = o;
}

// ---------------- prep: src -> bf16 raw + bf16 L2-normalized ----------------
__global__ __launch_bounds__(256) void prep_k(const float* __restrict__ src,
    __bf16* __restrict__ srcb, __bf16* __restrict__ srcnb)
{
    int w = threadIdx.x >> 6, lane = threadIdx.x & 63;
    size_t token = blockIdx.x * 4 + w;
    const float* p = src + token * 512 + lane * 8;
    f32x4 a0 = *(const f32x4*)p;
    f32x4 a1 = *(const f32x4*)(p + 4);
    float s = a0[0]*a0[0]+a0[1]*a0[1]+a0[2]*a0[2]+a0[3]*a0[3]
            + a1[0]*a1[0]+a1[1]*a1[1]+a1[2]*a1[2]+a1[3]*a1[3];
#pragma unroll
    for (int off = 32; off; off >>= 1) s += __shfl_xor(s, off);
    float rs = rsqrtf(s);
    bf16x8 vb, vn;
#pragma unroll
    for (int q = 0; q < 4; q++) {
        vb[q]   = (__bf16)a0[q];      vn[q]   = (__bf16)(a0[q]*rs);
        vb[q+4] = (__bf16)a1[q];      vn[q+4] = (__bf16)(a1[q]*rs);
    }
    *(bf16x8*)&srcb[token*512 + lane*8]  = vb;
    *(bf16x8*)&srcnb[token*512 + lane*8] = vn;
}

// ---------------- bf16 MFMA NT GEMM, BK=64, XOR-swizzled LDS, bf16 out ----------------
// C[m,n] = sum_k A[m,k]*B[n,k]; 128x128 tile, 4 waves 2x2, 16x16x32 MFMA.
// AFFINE: A staged with per-column (K) affine from coef (K must be 512).
template<bool AFFINE, bool GELU>
__global__ __launch_bounds__(256) void gemm_k(
    const __bf16* __restrict__ A, const __bf16* __restrict__ B, __bf16* __restrict__ C,
    int N, int K, const float* __restrict__ bias, const float* __restrict__ coef)
{
    __shared__ __bf16 As[8192];   // [128][64], seg XOR-swizzled
    __shared__ __bf16 Bs[8192];
    const int tid = threadIdx.x, lane = tid & 63, w = tid >> 6;
    const int wr = w >> 1, wc = w & 1;
    const int m0 = blockIdx.y * 128, n0 = blockIdx.x * 128;
    const int fr = lane & 15, fq = lane >> 4;
    const int grow = 8*w + (lane >> 3);
    const int gcol = ((lane & 7) ^ (lane >> 3)) * 8;
    const __bf16* gB = B + (size_t)(n0 + grow) * K + gcol;
    const __bf16* gA = A + (size_t)(m0 + grow) * K + gcol;
    __bf16* ldsA = As + 8*w*64 + lane*8;
    __bf16* ldsB = Bs + 8*w*64 + lane*8;

    f32x4 acc[4][4];
#pragma unroll
    for (int i = 0; i < 4; i++)
#pragma unroll
        for (int j = 0; j < 4; j++) acc[i][j] = (f32x4){0.f,0.f,0.f,0.f};

    for (int k0 = 0; k0 < K; k0 += 64) {
        if (!AFFINE) {
#pragma unroll
            for (int i = 0; i < 4; i++)
                load_lds16(gA + k0 + (size_t)(32*i)*K, ldsA + i*2048);
        } else {
            const int r = tid >> 3, cseg = tid & 7;
            const float* scp = coef + k0 + cseg*8;
            const float* shp = coef + 512 + k0 + cseg*8;
            f32x4 sc0 = *(const f32x4*)scp, sc1 = *(const f32x4*)(scp+4);
            f32x4 sh0 = *(const f32x4*)shp, sh1 = *(const f32x4*)(shp+4);
#pragma unroll
            for (int i = 0; i < 4; i++) {
                int row = 32*i + r;
                bf16x8 a = *(const bf16x8*)&A[(size_t)(m0+row)*512 + k0 + cseg*8];
                bf16x8 v;
#pragma unroll
                for (int q = 0; q < 4; q++) {
                    v[q]   = (__bf16)fmaf((float)a[q],   sc0[q], sh0[q]);
                    v[q+4] = (__bf16)fmaf((float)a[q+4], sc1[q], sh1[q]);
                }
                *(bf16x8*)&As[row*64 + ((cseg ^ (r & 7)) * 8)] = v;
            }
        }
#pragma unroll
        for (int i = 0; i < 4; i++)
            load_lds16(gB + k0 + (size_t)(32*i)*K, ldsB + i*2048);
        __syncthreads();
#pragma unroll
        for (int kk = 0; kk < 2; kk++) {
            bf16x8 af[4], bfv[4];
#pragma unroll
            for (int i = 0; i < 4; i++)
                af[i] = *(bf16x8*)&As[(wr*64 + i*16 + fr)*64 + (((kk*4+fq) ^ (fr&7))*8)];
#pragma unroll
            for (int j = 0; j < 4; j++)
                bfv[j] = *(bf16x8*)&Bs[(wc*64 + j*16 + fr)*64 + (((kk*4+fq) ^ (fr&7))*8)];
#pragma unroll
            for (int i = 0; i < 4; i++)
#pragma unroll
                for (int j = 0; j < 4; j++)
                    acc[i][j] = __builtin_amdgcn_mfma_f32_16x16x32_bf16(af[i], bfv[j], acc[i][j], 0, 0, 0);
        }
        __syncthreads();
    }
    const int r4 = lane >> 4, cc = lane & 15;
#pragma unroll
    for (int i = 0; i < 4; i++) {
#pragma unroll
        for (int r = 0; r < 4; r++) {
            int m = m0 + wr*64 + i*16 + r4*4 + r;
#pragma unroll
            for (int j = 0; j < 4; j++) {
                int n = n0 + wc*64 + j*16 + cc;
                float v = acc[i][j][r] + bias[n];
                if (GELU) v = gelu_f(v);
                C[(size_t)m * N + n] = (__bf16)v;
            }
        }
    }
}

// ---------------- dual-source W2 GEMM: out = H1*B1^T + H2*B2^T + b1 + b2 + resid ----------------
// K = 2048 per source; N = 512; f32 out + final-BN stats via atomics.
__global__ __launch_bounds__(256) void gemm2_k(
    const __bf16* __restrict__ A1, const __bf16* __restrict__ A2,
    const __bf16* __restrict__ B1, const __bf16* __restrict__ B2,
    float* __restrict__ C, const float* __restrict__ b1, const float* __restrict__ b2,
    const float* __restrict__ resid, float* __restrict__ st)
{
    __shared__ __bf16 As[8192];
    __shared__ __bf16 Bs[8192];
    const int tid = threadIdx.x, lane = tid & 63, w = tid >> 6;
    const int wr = w >> 1, wc = w & 1;
    const int m0 = blockIdx.y * 128, n0 = blockIdx.x * 128;
    const int fr = lane & 15, fq = lane >> 4;
    const int grow = 8*w + (lane >> 3);
    const int gcol = ((lane & 7) ^ (lane >> 3)) * 8;
    const int K = 2048;
    __bf16* ldsA = As + 8*w*64 + lane*8;
    __bf16* ldsB = Bs + 8*w*64 + lane*8;

    f32x4 acc[4][4];
#pragma unroll
    for (int i = 0; i < 4; i++)
#pragma unroll
        for (int j = 0; j < 4; j++) acc[i][j] = (f32x4){0.f,0.f,0.f,0.f};

#pragma unroll 1
    for (int half = 0; half < 2; half++) {
        const __bf16* gA = (half ? A2 : A1) + (size_t)(m0 + grow) * K + gcol;
        const __bf16* gB = (half ? B2 : B1) + (size_t)(n0 + grow) * K + gcol;
        for (int k0 = 0; k0 < K; k0 += 64) {
#pragma unroll
            for (int i = 0; i < 4; i++) {
                load_lds16(gA + k0 + (size_t)(32*i)*K, ldsA + i*2048);
                load_lds16(gB + k0 + (size_t)(32*i)*K, ldsB + i*2048);
            }
            __syncthreads();
#pragma unroll
            for (int kk = 0; kk < 2; kk++) {
                bf16x8 af[4], bfv[4];
#pragma unroll
                for (int i = 0; i < 4; i++)
                    af[i] = *(bf16x8*)&As[(wr*64 + i*16 + fr)*64 + (((kk*4+fq) ^ (fr&7))*8)];
#pragma unroll
                for (int j = 0; j < 4; j++)
                    bfv[j] = *(bf16x8*)&Bs[(wc*64 + j*16 + fr)*64 + (((kk*4+fq) ^ (fr&7))*8)];
#pragma unroll
                for (int i = 0; i < 4; i++)
#pragma unroll
                    for (int j = 0; j < 4; j++)
                        acc[i][j] = __builtin_amdgcn_mfma_f32_16x16x32_bf16(af[i], bfv[j], acc[i][j], 0, 0, 0);
            }
            __syncthreads();
        }
    }
    const int r4 = lane >> 4, cc = lane & 15;
    float cs[4] = {0,0,0,0}, cq[4] = {0,0,0,0};
#pragma unroll
    for (int i = 0; i < 4; i++) {
#pragma unroll
        for (int r = 0; r < 4; r++) {
            int m = m0 + wr*64 + i*16 + r4*4 + r;
#pragma unroll
            for (int j = 0; j < 4; j++) {
                int n = n0 + wc*64 + j*16 + cc;
                size_t idx = (size_t)m * 512 + n;
                float v = acc[i][j][r] + b1[n] + b2[n] + resid[idx];
                C[idx] = v;
                cs[j] += v; cq[j] = fmaf(v, v, cq[j]);
            }
        }
    }
#pragma unroll
    for (int j = 0; j < 4; j++) {
        cs[j] += __shfl_xor(cs[j], 16); cs[j] += __shfl_xor(cs[j], 32);
        cq[j] += __shfl_xor(cq[j], 16); cq[j] += __shfl_xor(cq[j], 32);
    }
    if (r4 == 0) {
#pragma unroll
        for (int j = 0; j < 4; j++) {
            int n = n0 + wc*64 + j*16 + cc;
            atomicAdd(&st[n], cs[j]);
            atomicAdd(&st[512 + n], cq[j]);
        }
    }
}

// ---------------- exponential-decay causal scan (replaces FFT), in place, bf16 ----------------
__global__ __launch_bounds__(256) void decay_scan_k(__bf16* __restrict__ QKb, const float* __restrict__ alpha)
{
    int g = blockIdx.x * 256 + threadIdx.x;   // 131072 threads
    int bn = g >> 10, e = g & 1023;
    float a = 1.f / (1.f + expf(-alpha[e & 63]));
    float rr = 1.f - a;
    __bf16* p = QKb + (size_t)bn * SEQ * 1024 + e;
    float P = 0.f, pw = 1.f;
    for (int t = 0; t < SEQ; t++) {
        P += pw * (float)p[(size_t)t*1024];
        p[(size_t)t*1024] = (__bf16)P;
        pw *= rr;
    }
    float f = a;
    for (int t = SEQ-1; t >= 0; t--) {
        p[(size_t)t*1024] = (__bf16)((float)p[(size_t)t*1024] * f);
        f *= rr;
    }
}

// ---------------- hidden-axis attention, MFMA. block=(bn,nh), 256 thr, bf16 out ----------------
__global__ __launch_bounds__(256) void hidden_attn_mfma_k(
    const __bf16* __restrict__ QKb, const __bf16* __restrict__ Vb, __bf16* __restrict__ OHb)
{
    __shared__ __bf16 smem[25600];
    __bf16* Qt = smem;             // 64 x 200 (phase 1)  [e][t]
    __bf16* Kt = smem + 12800;     // 64 x 200            [f][t]
    __bf16* Ps = smem;             // 64 x 72  (phase 2)  [e][f]
    __bf16* Vs = smem + 4608;      // 192 x 72            [t][f]
    const int bn = blockIdx.x >> 3, nh = blockIdx.x & 7;
    const int tid = threadIdx.x, lane = tid & 63, w = tid >> 6;
    const int fr = lane & 15, fq = lane >> 4;
    const size_t rowbase = (size_t)bn * SEQ;

    for (int i = tid; i < 12288; i += 256) {          // transpose-stage q^T,k^T
        int t = i >> 6, j = i & 63;
        const __bf16* g = QKb + (rowbase + t)*1024 + nh*64 + j;
        Qt[j*200 + t] = g[0];
        Kt[j*200 + t] = g[512];
    }
    __syncthreads();

    f32x4 acc[4];
#pragma unroll
    for (int i = 0; i < 4; i++) acc[i] = (f32x4){0.f,0.f,0.f,0.f};
#pragma unroll
    for (int kc = 0; kc < 6; kc++) {
        bf16x8 a = *(bf16x8*)&Qt[(w*16 + fr)*200 + kc*32 + fq*8];
#pragma unroll
        for (int nt = 0; nt < 4; nt++) {
            bf16x8 b = *(bf16x8*)&Kt[(nt*16 + fr)*200 + kc*32 + fq*8];
            acc[nt] = __builtin_amdgcn_mfma_f32_16x16x32_bf16(a, b, acc[nt], 0, 0, 0);
        }
    }
    const float sc = 13.856406460551018f;   // sqrt(192)
    float pn[4][4];
#pragma unroll
    for (int reg = 0; reg < 4; reg++) {
        float m = -1e30f;
#pragma unroll
        for (int nt = 0; nt < 4; nt++) { acc[nt][reg] *= sc; m = fmaxf(m, acc[nt][reg]); }
#pragma unroll
        for (int off = 1; off < 16; off <<= 1) m = fmaxf(m, __shfl_xor(m, off));
        float l = 0.f;
#pragma unroll
        for (int nt = 0; nt < 4; nt++) { pn[nt][reg] = __expf(acc[nt][reg] - m); l += pn[nt][reg]; }
#pragma unroll
        for (int off = 1; off < 16; off <<= 1) l += __shfl_xor(l, off);
        float inv = 1.f / l;
#pragma unroll
        for (int nt = 0; nt < 4; nt++) pn[nt][reg] *= inv;
    }
    __syncthreads();                                   // Qt/Kt dead
#pragma unroll
    for (int nt = 0; nt < 4; nt++)
#pragma unroll
        for (int reg = 0; reg < 4; reg++)
            Ps[(w*16 + fq*4 + reg)*72 + nt*16 + fr] = (__bf16)pn[nt][reg];
    for (int i = tid; i < 1536; i += 256) {            // stage V natural
        int t = i >> 3, s = i & 7;
        *(bf16x8*)&Vs[t*72 + s*8] = *(const bf16x8*)&Vb[(rowbase+t)*512 + nh*64 + s*8];
    }
    __syncthreads();

    f32x4 o[3][4];
#pragma unroll
    for (int i = 0; i < 3; i++)
#pragma unroll
        for (int j = 0; j < 4; j++) o[i][j] = (f32x4){0.f,0.f,0.f,0.f};
#pragma unroll
    for (int kc = 0; kc < 2; kc++) {
        bf16x8 av[3];
#pragma unroll
        for (int mt = 0; mt < 3; mt++)
            av[mt] = *(bf16x8*)&Vs[(48*w + mt*16 + fr)*72 + kc*32 + fq*8];
#pragma unroll
        for (int nt = 0; nt < 4; nt++) {
            bf16x8 b = *(bf16x8*)&Ps[(nt*16 + fr)*72 + kc*32 + fq*8];
#pragma unroll
            for (int mt = 0; mt < 3; mt++)
                o[mt][nt] = __builtin_amdgcn_mfma_f32_16x16x32_bf16(av[mt], b, o[mt][nt], 0, 0, 0);
        }
    }
    __bf16* obase = OHb + ((size_t)(bn*8 + nh)) * SEQ * 64;
#pragma unroll
    for (int mt = 0; mt < 3; mt++)
#pragma unroll
        for (int reg = 0; reg < 4; reg++) {
            int t = 48*w + mt*16 + fq*4 + reg;
#pragma unroll
            for (int nt = 0; nt < 4; nt++)
                obase[(size_t)t*64 + nt*16 + fr] = (__bf16)o[mt][nt][reg];
        }
}

// ---------------- token-axis attention, MFMA. block=(bn,nh), 256 thr, bf16 out ----------------
__global__ __launch_bounds__(256) void token_attn_mfma_k(
    const __bf16* __restrict__ QKb, const __bf16* __restrict__ Vb, __bf16* __restrict__ OT)
{
    __shared__ __bf16 smem[27648];
    __bf16* Qs = smem;              // 192 x 72 (phase A) [e][d]
    __bf16* Ks = smem + 13824;      // 192 x 72           [f][d]
    __bf16* Vt = smem;              // 64 x 200 (phase B) [d][f]
    __bf16* Pw = smem + 12800;      // 4 waves x (48 x 72)
    const int bn = blockIdx.x >> 3, nh = blockIdx.x & 7;
    const int tid = threadIdx.x, lane = tid & 63, w = tid >> 6;
    const int fr = lane & 15, fq = lane >> 4;
    const size_t rowbase = (size_t)bn * SEQ;

    for (int i = tid; i < 1536; i += 256) {
        int t = i >> 3, s = i & 7;
        const __bf16* g = QKb + (rowbase + t)*1024 + nh*64;
        *(bf16x8*)&Qs[t*72 + s*8] = *(const bf16x8*)&g[s*8];
        *(bf16x8*)&Ks[t*72 + s*8] = *(const bf16x8*)&g[512 + s*8];
    }
    __syncthreads();

    f32x4 S[3][12];
#pragma unroll
    for (int i = 0; i < 3; i++)
#pragma unroll
        for (int j = 0; j < 12; j++) S[i][j] = (f32x4){0.f,0.f,0.f,0.f};
#pragma unroll
    for (int kc = 0; kc < 2; kc++) {
        bf16x8 aq[3];
#pragma unroll
        for (int mt = 0; mt < 3; mt++)
            aq[mt] = *(bf16x8*)&Qs[(48*w + mt*16 + fr)*72 + kc*32 + fq*8];
#pragma unroll
        for (int nt = 0; nt < 12; nt++) {
            bf16x8 b = *(bf16x8*)&Ks[(nt*16 + fr)*72 + kc*32 + fq*8];
#pragma unroll
            for (int mt = 0; mt < 3; mt++)
                S[mt][nt] = __builtin_amdgcn_mfma_f32_16x16x32_bf16(aq[mt], b, S[mt][nt], 0, 0, 0);
        }
    }
#pragma unroll
    for (int mt = 0; mt < 3; mt++)
#pragma unroll
        for (int reg = 0; reg < 4; reg++) {
            float m = -1e30f;
#pragma unroll
            for (int nt = 0; nt < 12; nt++) { S[mt][nt][reg] *= 8.f; m = fmaxf(m, S[mt][nt][reg]); }
#pragma unroll
            for (int off = 1; off < 16; off <<= 1) m = fmaxf(m, __shfl_xor(m, off));
            float l = 0.f;
#pragma unroll
            for (int nt = 0; nt < 12; nt++) { S[mt][nt][reg] = __expf(S[mt][nt][reg] - m); l += S[mt][nt][reg]; }
#pragma unroll
            for (int off = 1; off < 16; off <<= 1) l += __shfl_xor(l, off);
            float inv = 1.f / l;
#pragma unroll
            for (int nt = 0; nt < 12; nt++) S[mt][nt][reg] *= inv;
        }
    __syncthreads();                                   // Qs/Ks dead
    for (int i = tid; i < 12288; i += 256) {           // transpose-stage V^T
        int t = i >> 6, d = i & 63;
        Vt[d*200 + t] = Vb[(rowbase + t)*512 + nh*64 + d];
    }
    __syncthreads();

    f32x4 O[3][4];
#pragma unroll
    for (int i = 0; i < 3; i++)
#pragma unroll
        for (int j = 0; j < 4; j++) O[i][j] = (f32x4){0.f,0.f,0.f,0.f};
    __bf16* myP = Pw + w*3456;
#pragma unroll
    for (int fc = 0; fc < 3; fc++) {
#pragma unroll
        for (int mt = 0; mt < 3; mt++)
#pragma unroll
            for (int j = 0; j < 4; j++)
#pragma unroll
                for (int reg = 0; reg < 4; reg++)
                    myP[(mt*16 + fq*4 + reg)*72 + j*16 + fr] = (__bf16)S[mt][fc*4 + j][reg];
        // per-wave LDS region; DS ops are in-order per wave -> no barrier needed
#pragma unroll
        for (int kc = 0; kc < 2; kc++) {
            bf16x8 ap[3];
#pragma unroll
            for (int mt = 0; mt < 3; mt++)
                ap[mt] = *(bf16x8*)&myP[(mt*16 + fr)*72 + kc*32 + fq*8];
#pragma unroll
            for (int dt = 0; dt < 4; dt++) {
                bf16x8 b = *(bf16x8*)&Vt[(dt*16 + fr)*200 + fc*64 + kc*32 + fq*8];
#pragma unroll
                for (int mt = 0; mt < 3; mt++)
                    O[mt][dt] = __builtin_amdgcn_mfma_f32_16x16x32_bf16(ap[mt], b, O[mt][dt], 0, 0, 0);
            }
        }
    }
    __bf16* obase = OT + ((size_t)(bn*8 + nh)) * SEQ * 64;
#pragma unroll
    for (int mt = 0; mt < 3; mt++)
#pragma unroll
        for (int reg = 0; reg < 4; reg++) {
            int e = 48*w + mt*16 + fq*4 + reg;
#pragma unroll
            for (int dt = 0; dt < 4; dt++)
                obase[(size_t)e*64 + dt*16 + fr] = (__bf16)O[mt][dt][reg];
        }
}

// ---------------- BatchNorm helpers (channel = flat % 512) ----------------
__global__ __launch_bounds__(256) void bn_stats_bf16_k(const __bf16* __restrict__ x, float* __restrict__ st)
{
    int col8 = threadIdx.x & 63;           // 8 channels per thread
    int rl   = threadIdx.x >> 6;           // 0..3
    size_t r0 = (size_t)blockIdx.x * 128;  // 192 blocks x 128 rows
    float s[8] = {0,0,0,0,0,0,0,0}, q[8] = {0,0,0,0,0,0,0,0};
    for (int r = rl; r < 128; r += 4) {
        bf16x8 v = *(const bf16x8*)&x[(r0 + r)*512 + col8*8];
#pragma unroll
        for (int j = 0; j < 8; j++) { float f = (float)v[j]; s[j] += f; q[j] = fmaf(f, f, q[j]); }
    }
#pragma unroll
    for (int j = 0; j < 8; j++) {
        atomicAdd(&st[col8*8 + j], s[j]);
        atomicAdd(&st[512 + col8*8 + j], q[j]);
    }
}

__global__ void bn_coef_k(const float* __restrict__ st, const float* __restrict__ g,
                          const float* __restrict__ b, float* __restrict__ coef)
{
    int c = threadIdx.x;   // 512
    float mean = st[c] * (1.f/24576.f);
    float var  = st[512+c] * (1.f/24576.f) - mean*mean;
    float sc = rsqrtf(var + EPS) * g[c];
    coef[c] = sc;
    coef[512 + c] = b[c] - mean * sc;
}

// in-place BN apply on bf16 buffer
__global__ __launch_bounds__(256) void bn_apply_ip_k(__bf16* __restrict__ x, const float* __restrict__ st,
    const float* __restrict__ g, const float* __restrict__ b)
{
    size_t i = (size_t)blockIdx.x * 256 + threadIdx.x;   // 6144 blocks x 8 elems
    int col8 = i & 63;
    bf16x8 v = ((bf16x8*)x)[i];
    bf16x8 o;
#pragma unroll
    for (int j = 0; j < 8; j++) {
        int c = col8*8 + j;
        float mean = st[c] * (1.f/24576.f);
        float var  = st[512+c] * (1.f/24576.f) - mean*mean;
        o[j] = (__bf16)(((float)v[j] - mean) * rsqrtf(var + EPS) * g[c] + b[c]);
    }
    ((bf16x8*)x)[i] = o;
}

__global__ __launch_bounds__(256) void bn_apply4_k(const float* __restrict__ x, const float* __restrict__ st,
    const float* __restrict__ g, const float* __restrict__ b, float* __restrict__ out)
{
    size_t i = (size_t)blockIdx.x * 256 + threadIdx.x;   // 12288 blocks
    int col4 = i & 127;
    f32x4 v = ((const f32x4*)x)[i];
    f32x4 sm = ((const f32x4*)st)[col4];
    f32x4 sq = ((const f32x4*)(st + 512))[col4];
    f32x4 o;
#pragma unroll
    for (int j = 0; j < 4; j++) {
        int c = col4*4 + j;
        float mean = sm[j] * (1.f/24576.f);
        float var  = sq[j] * (1.f/24576.f) - mean*mean;
        o[j] = (v[j] - mean) * rsqrtf(var + EPS) * g[c] + b[c];
    }
    ((f32x4*)out)[i] = o;
}

extern "C" void kernel_launch(void* const* d_in, const int* in_sizes, int n_in,
                              void* d_out, int out_size, void* d_ws, size_t ws_size,
                              hipStream_t stream)
{
    const float* src    = (const float*)d_in[0];
    const float* qk_w   = (const float*)d_in[1];
    const float* qk_b   = (const float*)d_in[2];
    const float* v_w    = (const float*)d_in[3];
    const float* v_b    = (const float*)d_in[4];
    const float* alpha  = (const float*)d_in[5];
    const float* g_pre1 = (const float*)d_in[6];
    const float* b_pre1 = (const float*)d_in[7];
    const float* g_pre2 = (const float*)d_in[8];
    const float* b_pre2 = (const float*)d_in[9];
    const float* ff1_w1 = (const float*)d_in[10];
    const float* ff1_b1 = (const float*)d_in[11];
    const float* ff1_w2 = (const float*)d_in[12];
    const float* ff1_b2 = (const float*)d_in[13];
    const float* ff2_w1 = (const float*)d_in[14];
    const float* ff2_b1 = (const float*)d_in[15];
    const float* ff2_w2 = (const float*)d_in[16];
    const float* ff2_b2 = (const float*)d_in[17];
    const float* g_attn = (const float*)d_in[18];
    const float* b_attn = (const float*)d_in[19];
    float* out = (float*)d_out;

    // ws layout (bf16 units) — ~185 MB total:
    // weights | span{srcb,srcnb,QKb,Vb} (H1+H2 overlay) | OHbf | o3bf | stats
    __bf16* wq   = (__bf16*)d_ws;                       //  524288
    __bf16* wv   = wq  + 524288;                        //  262144
    __bf16* w11  = wv  + 262144;                        // 1048576
    __bf16* w12  = w11 + 1048576;                       // 1048576
    __bf16* w21  = w12 + 1048576;                       // 1048576
    __bf16* w22  = w21 + 1048576;                       // 1048576
    __bf16* srcb  = w22 + 1048576;                      // 12582912
    __bf16* srcnb = srcb + (size_t)NTOK*512;            // 12582912
    __bf16* QKb   = srcnb + (size_t)NTOK*512;           // 25165824
    __bf16* Vb    = QKb + (size_t)NTOK*1024;            // 12582912
    __bf16* OHbf  = Vb + (size_t)NTOK*512;              // 12582912 (becomes o2 in place)
    __bf16* o3bf  = OHbf + (size_t)NTOK*512;            // 12582912
    float*  stats = (float*)(o3bf + (size_t)NTOK*512);  // 3072 f32
    float*  coef0 = stats + 3072;                       // 1024 f32
    // FFN hidden (per 12288-row chunk) overlays the dead srcb..Vb span:
    __bf16* H1 = srcb;                                  // 12288 x 2048
    __bf16* H2 = H1 + (size_t)12288*2048;               // 12288 x 2048
    float *st0 = stats, *st1 = stats + 1024, *st2 = stats + 2048;

    hipMemsetAsync(stats, 0, 3*1024*sizeof(float), stream);

    // 0. one-time bf16 conversions
    cvt_k<<<512,  256, 0, stream>>>(qk_w,   wq);
    cvt_k<<<256,  256, 0, stream>>>(v_w,    wv);
    cvt_k<<<1024, 256, 0, stream>>>(ff1_w1, w11);
    cvt_k<<<1024, 256, 0, stream>>>(ff1_w2, w12);
    cvt_k<<<1024, 256, 0, stream>>>(ff2_w1, w21);
    cvt_k<<<1024, 256, 0, stream>>>(ff2_w2, w22);
    prep_k<<<NTOK/4, 256, 0, stream>>>(src, srcb, srcnb);

    // 1. projections
    gemm_k<false,false><<<dim3(8, 192), 256, 0, stream>>>(srcnb, wq, QKb, 1024, 512, qk_b, nullptr);
    gemm_k<false,false><<<dim3(4, 192), 256, 0, stream>>>(srcb,  wv, Vb,  512,  512, v_b,  nullptr);

    // 2. hidden-axis attention on UN-decayed q,k -> bf16
    hidden_attn_mfma_k<<<1024, 256, 0, stream>>>(QKb, Vb, OHbf);

    // 3. decay scan in place, then MFMA token attention -> bf16 o3
    decay_scan_k<<<512, 256, 0, stream>>>(QKb, alpha);
    token_attn_mfma_k<<<1024, 256, 0, stream>>>(QKb, Vb, o3bf);

    // 4. BN stats (bf16 inputs); o3-BN folds into FF1-W1 staging via coef0;
    //    o2-BN applied in place on OHbf
    bn_stats_bf16_k<<<192, 256, 0, stream>>>(o3bf, st0);   // out_tok -> pre2
    bn_stats_bf16_k<<<192, 256, 0, stream>>>(OHbf, st1);   // out_hid -> pre1
    bn_coef_k<<<1, 512, 0, stream>>>(st0, g_pre2, b_pre2, coef0);
    bn_apply_ip_k<<<6144, 256, 0, stream>>>(OHbf, st1, g_pre1, b_pre1);

    // 5. FFN in 2 chunks of 12288 rows; H1/H2 overlay the dead srcb..Vb span.
    //    gemm2 fuses both W2 matmuls + biases + residual + final-BN stats.
    for (int ch = 0; ch < 2; ch++) {
        size_t off = (size_t)ch * 12288 * 512;
        gemm_k<true, true><<<dim3(16, 96), 256, 0, stream>>>(o3bf + off, w11, H1, 2048, 512, ff1_b1, coef0);
        gemm_k<false,true><<<dim3(16, 96), 256, 0, stream>>>(OHbf + off, w21, H2, 2048, 512, ff2_b1, nullptr);
        gemm2_k<<<dim3(4, 96), 256, 0, stream>>>(H1, H2, w12, w22, out + off,
                                                 ff1_b2, ff2_b2, src + off, st2);
    }

    // 6. final BN (in place on d_out)
    bn_apply4_k<<<12288, 256, 0, stream>>>(out, st2, g_attn, b_attn, out);
}

// Round 6
// 786.808 us; speedup vs baseline: 1.2929x; 1.2929x over previous
//
#include <hip/hip_runtime.h>
#include <math.h>

#define SEQ 192
#define NTOK 24576      // 128*192
#define EPS 1e-5f

typedef __bf16 bf16x8 __attribute__((ext_vector_type(8)));
typedef __bf16 bf16x4 __attribute__((ext_vector_type(4)));
typedef float  f32x4  __attribute__((ext_vector_type(4)));

__device__ __forceinline__ void load_lds16(const __bf16* g, __bf16* l) {
    __builtin_amdgcn_global_load_lds(
        (const __attribute__((address_space(1))) uint32_t*)g,
        (__attribute__((address_space(3))) uint32_t*)l, 16, 0, 0);
}

// tanh-form GELU via sigmoid: x*sigmoid(1.5958*(x+0.044715 x^3))
__device__ __forceinline__ float gelu_f(float x) {
    float z = 1.5957691216057308f * x * fmaf(0.044715f, x*x, 1.f);
    float e = __expf(-z);
    return x * __builtin_amdgcn_rcpf(1.f + e);
}

// ---------------- f32 -> bf16 bulk convert (weights) ----------------
__global__ __launch_bounds__(256) void cvt_k(const float* __restrict__ x, __bf16* __restrict__ y)
{
    int i = blockIdx.x * 256 + threadIdx.x;
    f32x4 v = ((const f32x4*)x)[i];
    bf16x4 o;
    o[0]=(__bf16)v[0]; o[1]=(__bf16)v[1]; o[2]=(__bf16)v[2]; o[3]=(__bf16)v[3];
    ((bf16x4*)y)[i] = o;
}

// ---------------- prep: src -> bf16 raw + bf16 L2-normalized ----------------
__global__ __launch_bounds__(256) void prep_k(const float* __restrict__ src,
    __bf16* __restrict__ srcb, __bf16* __restrict__ srcnb)
{
    int w = threadIdx.x >> 6, lane = threadIdx.x & 63;
    size_t token = blockIdx.x * 4 + w;
    const float* p = src + token * 512 + lane * 8;
    f32x4 a0 = *(const f32x4*)p;
    f32x4 a1 = *(const f32x4*)(p + 4);
    float s = a0[0]*a0[0]+a0[1]*a0[1]+a0[2]*a0[2]+a0[3]*a0[3]
            + a1[0]*a1[0]+a1[1]*a1[1]+a1[2]*a1[2]+a1[3]*a1[3];
#pragma unroll
    for (int off = 32; off; off >>= 1) s += __shfl_xor(s, off);
    float rs = rsqrtf(s);
    bf16x8 vb, vn;
#pragma unroll
    for (int q = 0; q < 4; q++) {
        vb[q]   = (__bf16)a0[q];      vn[q]   = (__bf16)(a0[q]*rs);
        vb[q+4] = (__bf16)a1[q];      vn[q+4] = (__bf16)(a1[q]*rs);
    }
    *(bf16x8*)&srcb[token*512 + lane*8]  = vb;
    *(bf16x8*)&srcnb[token*512 + lane*8] = vn;
}

// ---------------- bf16 MFMA NT GEMM, BK=64, XOR-swizzled LDS, bf16 out ----------------
// C[m,n] = sum_k A[m,k]*B[n,k]; 128x128 tile, 4 waves 2x2, 16x16x32 MFMA.
// AFFINE: A staged with per-column (K) affine from coef (K must be 512).
template<bool AFFINE, bool GELU>
__global__ __launch_bounds__(256) void gemm_k(
    const __bf16* __restrict__ A, const __bf16* __restrict__ B, __bf16* __restrict__ C,
    int N, int K, const float* __restrict__ bias, const float* __restrict__ coef)
{
    __shared__ __bf16 As[8192];   // [128][64], seg XOR-swizzled
    __shared__ __bf16 Bs[8192];
    const int tid = threadIdx.x, lane = tid & 63, w = tid >> 6;
    const int wr = w >> 1, wc = w & 1;
    const int m0 = blockIdx.y * 128, n0 = blockIdx.x * 128;
    const int fr = lane & 15, fq = lane >> 4;
    const int grow = 8*w + (lane >> 3);
    const int gcol = ((lane & 7) ^ (lane >> 3)) * 8;
    const __bf16* gB = B + (size_t)(n0 + grow) * K + gcol;
    const __bf16* gA = A + (size_t)(m0 + grow) * K + gcol;
    __bf16* ldsA = As + 8*w*64 + lane*8;
    __bf16* ldsB = Bs + 8*w*64 + lane*8;

    f32x4 acc[4][4];
#pragma unroll
    for (int i = 0; i < 4; i++)
#pragma unroll
        for (int j = 0; j < 4; j++) acc[i][j] = (f32x4){0.f,0.f,0.f,0.f};

    for (int k0 = 0; k0 < K; k0 += 64) {
        if (!AFFINE) {
#pragma unroll
            for (int i = 0; i < 4; i++)
                load_lds16(gA + k0 + (size_t)(32*i)*K, ldsA + i*2048);
        } else {
            const int r = tid >> 3, cseg = tid & 7;
            const float* scp = coef + k0 + cseg*8;
            const float* shp = coef + 512 + k0 + cseg*8;
            f32x4 sc0 = *(const f32x4*)scp, sc1 = *(const f32x4*)(scp+4);
            f32x4 sh0 = *(const f32x4*)shp, sh1 = *(const f32x4*)(shp+4);
#pragma unroll
            for (int i = 0; i < 4; i++) {
                int row = 32*i + r;
                bf16x8 a = *(const bf16x8*)&A[(size_t)(m0+row)*512 + k0 + cseg*8];
                bf16x8 v;
#pragma unroll
                for (int q = 0; q < 4; q++) {
                    v[q]   = (__bf16)fmaf((float)a[q],   sc0[q], sh0[q]);
                    v[q+4] = (__bf16)fmaf((float)a[q+4], sc1[q], sh1[q]);
                }
                *(bf16x8*)&As[row*64 + ((cseg ^ (r & 7)) * 8)] = v;
            }
        }
#pragma unroll
        for (int i = 0; i < 4; i++)
            load_lds16(gB + k0 + (size_t)(32*i)*K, ldsB + i*2048);
        __syncthreads();
#pragma unroll
        for (int kk = 0; kk < 2; kk++) {
            bf16x8 af[4], bfv[4];
#pragma unroll
            for (int i = 0; i < 4; i++)
                af[i] = *(bf16x8*)&As[(wr*64 + i*16 + fr)*64 + (((kk*4+fq) ^ (fr&7))*8)];
#pragma unroll
            for (int j = 0; j < 4; j++)
                bfv[j] = *(bf16x8*)&Bs[(wc*64 + j*16 + fr)*64 + (((kk*4+fq) ^ (fr&7))*8)];
#pragma unroll
            for (int i = 0; i < 4; i++)
#pragma unroll
                for (int j = 0; j < 4; j++)
                    acc[i][j] = __builtin_amdgcn_mfma_f32_16x16x32_bf16(af[i], bfv[j], acc[i][j], 0, 0, 0);
        }
        __syncthreads();
    }
    const int r4 = lane >> 4, cc = lane & 15;
#pragma unroll
    for (int i = 0; i < 4; i++) {
#pragma unroll
        for (int r = 0; r < 4; r++) {
            int m = m0 + wr*64 + i*16 + r4*4 + r;
#pragma unroll
            for (int j = 0; j < 4; j++) {
                int n = n0 + wc*64 + j*16 + cc;
                float v = acc[i][j][r] + bias[n];
                if (GELU) v = gelu_f(v);
                C[(size_t)m * N + n] = (__bf16)v;
            }
        }
    }
}

// ---------------- dual-source W2 GEMM: out = H1*B1^T + H2*B2^T + b1 + b2 + resid ----------------
// K = 2048 per source; N = 512; f32 out + final-BN stats via atomics.
__global__ __launch_bounds__(256) void gemm2_k(
    const __bf16* __restrict__ A1, const __bf16* __restrict__ A2,
    const __bf16* __restrict__ B1, const __bf16* __restrict__ B2,
    float* __restrict__ C, const float* __restrict__ b1, const float* __restrict__ b2,
    const float* __restrict__ resid, float* __restrict__ st)
{
    __shared__ __bf16 As[8192];
    __shared__ __bf16 Bs[8192];
    const int tid = threadIdx.x, lane = tid & 63, w = tid >> 6;
    const int wr = w >> 1, wc = w & 1;
    const int m0 = blockIdx.y * 128, n0 = blockIdx.x * 128;
    const int fr = lane & 15, fq = lane >> 4;
    const int grow = 8*w + (lane >> 3);
    const int gcol = ((lane & 7) ^ (lane >> 3)) * 8;
    const int K = 2048;
    __bf16* ldsA = As + 8*w*64 + lane*8;
    __bf16* ldsB = Bs + 8*w*64 + lane*8;

    f32x4 acc[4][4];
#pragma unroll
    for (int i = 0; i < 4; i++)
#pragma unroll
        for (int j = 0; j < 4; j++) acc[i][j] = (f32x4){0.f,0.f,0.f,0.f};

#pragma unroll 1
    for (int half = 0; half < 2; half++) {
        const __bf16* gA = (half ? A2 : A1) + (size_t)(m0 + grow) * K + gcol;
        const __bf16* gB = (half ? B2 : B1) + (size_t)(n0 + grow) * K + gcol;
        for (int k0 = 0; k0 < K; k0 += 64) {
#pragma unroll
            for (int i = 0; i < 4; i++) {
                load_lds16(gA + k0 + (size_t)(32*i)*K, ldsA + i*2048);
                load_lds16(gB + k0 + (size_t)(32*i)*K, ldsB + i*2048);
            }
            __syncthreads();
#pragma unroll
            for (int kk = 0; kk < 2; kk++) {
                bf16x8 af[4], bfv[4];
#pragma unroll
                for (int i = 0; i < 4; i++)
                    af[i] = *(bf16x8*)&As[(wr*64 + i*16 + fr)*64 + (((kk*4+fq) ^ (fr&7))*8)];
#pragma unroll
                for (int j = 0; j < 4; j++)
                    bfv[j] = *(bf16x8*)&Bs[(wc*64 + j*16 + fr)*64 + (((kk*4+fq) ^ (fr&7))*8)];
#pragma unroll
                for (int i = 0; i < 4; i++)
#pragma unroll
                    for (int j = 0; j < 4; j++)
                        acc[i][j] = __builtin_amdgcn_mfma_f32_16x16x32_bf16(af[i], bfv[j], acc[i][j], 0, 0, 0);
            }
            __syncthreads();
        }
    }
    const int r4 = lane >> 4, cc = lane & 15;
    float cs[4] = {0,0,0,0}, cq[4] = {0,0,0,0};
#pragma unroll
    for (int i = 0; i < 4; i++) {
#pragma unroll
        for (int r = 0; r < 4; r++) {
            int m = m0 + wr*64 + i*16 + r4*4 + r;
#pragma unroll
            for (int j = 0; j < 4; j++) {
                int n = n0 + wc*64 + j*16 + cc;
                size_t idx = (size_t)m * 512 + n;
                float v = acc[i][j][r] + b1[n] + b2[n] + resid[idx];
                C[idx] = v;
                cs[j] += v; cq[j] = fmaf(v, v, cq[j]);
            }
        }
    }
#pragma unroll
    for (int j = 0; j < 4; j++) {
        cs[j] += __shfl_xor(cs[j], 16); cs[j] += __shfl_xor(cs[j], 32);
        cq[j] += __shfl_xor(cq[j], 16); cq[j] += __shfl_xor(cq[j], 32);
    }
    if (r4 == 0) {
#pragma unroll
        for (int j = 0; j < 4; j++) {
            int n = n0 + wc*64 + j*16 + cc;
            atomicAdd(&st[n], cs[j]);
            atomicAdd(&st[512 + n], cq[j]);
        }
    }
}

// ---------------- exponential-decay causal scan (replaces FFT), in place, bf16 ----------------
__global__ __launch_bounds__(256) void decay_scan_k(__bf16* __restrict__ QKb, const float* __restrict__ alpha)
{
    int g = blockIdx.x * 256 + threadIdx.x;   // 131072 threads
    int bn = g >> 10, e = g & 1023;
    float a = 1.f / (1.f + expf(-alpha[e & 63]));
    float rr = 1.f - a;
    __bf16* p = QKb + (size_t)bn * SEQ * 1024 + e;
    float P = 0.f, pw = 1.f;
    for (int t = 0; t < SEQ; t++) {
        P += pw * (float)p[(size_t)t*1024];
        p[(size_t)t*1024] = (__bf16)P;
        pw *= rr;
    }
    float f = a;
    for (int t = SEQ-1; t >= 0; t--) {
        p[(size_t)t*1024] = (__bf16)((float)p[(size_t)t*1024] * f);
        f *= rr;
    }
}

// ---------------- hidden-axis attention, MFMA. block=(bn,nh), 256 thr, bf16 out ----------------
__global__ __launch_bounds__(256) void hidden_attn_mfma_k(
    const __bf16* __restrict__ QKb, const __bf16* __restrict__ Vb, __bf16* __restrict__ OHb)
{
    __shared__ __bf16 smem[25600];
    __bf16* Qt = smem;             // 64 x 200 (phase 1)  [e][t]
    __bf16* Kt = smem + 12800;     // 64 x 200            [f][t]
    __bf16* Ps = smem;             // 64 x 72  (phase 2)  [e][f]
    __bf16* Vs = smem + 4608;      // 192 x 72            [t][f]
    const int bn = blockIdx.x >> 3, nh = blockIdx.x & 7;
    const int tid = threadIdx.x, lane = tid & 63, w = tid >> 6;
    const int fr = lane & 15, fq = lane >> 4;
    const size_t rowbase = (size_t)bn * SEQ;

    for (int i = tid; i < 12288; i += 256) {          // transpose-stage q^T,k^T
        int t = i >> 6, j = i & 63;
        const __bf16* g = QKb + (rowbase + t)*1024 + nh*64 + j;
        Qt[j*200 + t] = g[0];
        Kt[j*200 + t] = g[512];
    }
    __syncthreads();

    f32x4 acc[4];
#pragma unroll
    for (int i = 0; i < 4; i++) acc[i] = (f32x4){0.f,0.f,0.f,0.f};
#pragma unroll
    for (int kc = 0; kc < 6; kc++) {
        bf16x8 a = *(bf16x8*)&Qt[(w*16 + fr)*200 + kc*32 + fq*8];
#pragma unroll
        for (int nt = 0; nt < 4; nt++) {
            bf16x8 b = *(bf16x8*)&Kt[(nt*16 + fr)*200 + kc*32 + fq*8];
            acc[nt] = __builtin_amdgcn_mfma_f32_16x16x32_bf16(a, b, acc[nt], 0, 0, 0);
        }
    }
    const float sc = 13.856406460551018f;   // sqrt(192)
    float pn[4][4];
#pragma unroll
    for (int reg = 0; reg < 4; reg++) {
        float m = -1e30f;
#pragma unroll
        for (int nt = 0; nt < 4; nt++) { acc[nt][reg] *= sc; m = fmaxf(m, acc[nt][reg]); }
#pragma unroll
        for (int off = 1; off < 16; off <<= 1) m = fmaxf(m, __shfl_xor(m, off));
        float l = 0.f;
#pragma unroll
        for (int nt = 0; nt < 4; nt++) { pn[nt][reg] = __expf(acc[nt][reg] - m); l += pn[nt][reg]; }
#pragma unroll
        for (int off = 1; off < 16; off <<= 1) l += __shfl_xor(l, off);
        float inv = 1.f / l;
#pragma unroll
        for (int nt = 0; nt < 4; nt++) pn[nt][reg] *= inv;
    }
    __syncthreads();                                   // Qt/Kt dead
#pragma unroll
    for (int nt = 0; nt < 4; nt++)
#pragma unroll
        for (int reg = 0; reg < 4; reg++)
            Ps[(w*16 + fq*4 + reg)*72 + nt*16 + fr] = (__bf16)pn[nt][reg];
    for (int i = tid; i < 1536; i += 256) {            // stage V natural
        int t = i >> 3, s = i & 7;
        *(bf16x8*)&Vs[t*72 + s*8] = *(const bf16x8*)&Vb[(rowbase+t)*512 + nh*64 + s*8];
    }
    __syncthreads();

    f32x4 o[3][4];
#pragma unroll
    for (int i = 0; i < 3; i++)
#pragma unroll
        for (int j = 0; j < 4; j++) o[i][j] = (f32x4){0.f,0.f,0.f,0.f};
#pragma unroll
    for (int kc = 0; kc < 2; kc++) {
        bf16x8 av[3];
#pragma unroll
        for (int mt = 0; mt < 3; mt++)
            av[mt] = *(bf16x8*)&Vs[(48*w + mt*16 + fr)*72 + kc*32 + fq*8];
#pragma unroll
        for (int nt = 0; nt < 4; nt++) {
            bf16x8 b = *(bf16x8*)&Ps[(nt*16 + fr)*72 + kc*32 + fq*8];
#pragma unroll
            for (int mt = 0; mt < 3; mt++)
                o[mt][nt] = __builtin_amdgcn_mfma_f32_16x16x32_bf16(av[mt], b, o[mt][nt], 0, 0, 0);
        }
    }
    __bf16* obase = OHb + ((size_t)(bn*8 + nh)) * SEQ * 64;
#pragma unroll
    for (int mt = 0; mt < 3; mt++)
#pragma unroll
        for (int reg = 0; reg < 4; reg++) {
            int t = 48*w + mt*16 + fq*4 + reg;
#pragma unroll
            for (int nt = 0; nt < 4; nt++)
                obase[(size_t)t*64 + nt*16 + fr] = (__bf16)o[mt][nt][reg];
        }
}

// ---------------- token-axis attention, MFMA. block=(bn,nh), 256 thr, bf16 out ----------------
__global__ __launch_bounds__(256) void token_attn_mfma_k(
    const __bf16* __restrict__ QKb, const __bf16* __restrict__ Vb, __bf16* __restrict__ OT)
{
    __shared__ __bf16 smem[27648];
    __bf16* Qs = smem;              // 192 x 72 (phase A) [e][d]
    __bf16* Ks = smem + 13824;      // 192 x 72           [f][d]
    __bf16* Vt = smem;              // 64 x 200 (phase B) [d][f]
    __bf16* Pw = smem + 12800;      // 4 waves x (48 x 72)
    const int bn = blockIdx.x >> 3, nh = blockIdx.x & 7;
    const int tid = threadIdx.x, lane = tid & 63, w = tid >> 6;
    const int fr = lane & 15, fq = lane >> 4;
    const size_t rowbase = (size_t)bn * SEQ;

    for (int i = tid; i < 1536; i += 256) {
        int t = i >> 3, s = i & 7;
        const __bf16* g = QKb + (rowbase + t)*1024 + nh*64;
        *(bf16x8*)&Qs[t*72 + s*8] = *(const bf16x8*)&g[s*8];
        *(bf16x8*)&Ks[t*72 + s*8] = *(const bf16x8*)&g[512 + s*8];
    }
    __syncthreads();

    f32x4 S[3][12];
#pragma unroll
    for (int i = 0; i < 3; i++)
#pragma unroll
        for (int j = 0; j < 12; j++) S[i][j] = (f32x4){0.f,0.f,0.f,0.f};
#pragma unroll
    for (int kc = 0; kc < 2; kc++) {
        bf16x8 aq[3];
#pragma unroll
        for (int mt = 0; mt < 3; mt++)
            aq[mt] = *(bf16x8*)&Qs[(48*w + mt*16 + fr)*72 + kc*32 + fq*8];
#pragma unroll
        for (int nt = 0; nt < 12; nt++) {
            bf16x8 b = *(bf16x8*)&Ks[(nt*16 + fr)*72 + kc*32 + fq*8];
#pragma unroll
            for (int mt = 0; mt < 3; mt++)
                S[mt][nt] = __builtin_amdgcn_mfma_f32_16x16x32_bf16(aq[mt], b, S[mt][nt], 0, 0, 0);
        }
    }
#pragma unroll
    for (int mt = 0; mt < 3; mt++)
#pragma unroll
        for (int reg = 0; reg < 4; reg++) {
            float m = -1e30f;
#pragma unroll
            for (int nt = 0; nt < 12; nt++) { S[mt][nt][reg] *= 8.f; m = fmaxf(m, S[mt][nt][reg]); }
#pragma unroll
            for (int off = 1; off < 16; off <<= 1) m = fmaxf(m, __shfl_xor(m, off));
            float l = 0.f;
#pragma unroll
            for (int nt = 0; nt < 12; nt++) { S[mt][nt][reg] = __expf(S[mt][nt][reg] - m); l += S[mt][nt][reg]; }
#pragma unroll
            for (int off = 1; off < 16; off <<= 1) l += __shfl_xor(l, off);
            float inv = 1.f / l;
#pragma unroll
            for (int nt = 0; nt < 12; nt++) S[mt][nt][reg] *= inv;
        }
    __syncthreads();                                   // Qs/Ks dead
    for (int i = tid; i < 12288; i += 256) {           // transpose-stage V^T
        int t = i >> 6, d = i & 63;
        Vt[d*200 + t] = Vb[(rowbase + t)*512 + nh*64 + d];
    }
    __syncthreads();

    f32x4 O[3][4];
#pragma unroll
    for (int i = 0; i < 3; i++)
#pragma unroll
        for (int j = 0; j < 4; j++) O[i][j] = (f32x4){0.f,0.f,0.f,0.f};
    __bf16* myP = Pw + w*3456;
#pragma unroll
    for (int fc = 0; fc < 3; fc++) {
#pragma unroll
        for (int mt = 0; mt < 3; mt++)
#pragma unroll
            for (int j = 0; j < 4; j++)
#pragma unroll
                for (int reg = 0; reg < 4; reg++)
                    myP[(mt*16 + fq*4 + reg)*72 + j*16 + fr] = (__bf16)S[mt][fc*4 + j][reg];
        // per-wave LDS region; DS ops are in-order per wave -> no barrier needed
#pragma unroll
        for (int kc = 0; kc < 2; kc++) {
            bf16x8 ap[3];
#pragma unroll
            for (int mt = 0; mt < 3; mt++)
                ap[mt] = *(bf16x8*)&myP[(mt*16 + fr)*72 + kc*32 + fq*8];
#pragma unroll
            for (int dt = 0; dt < 4; dt++) {
                bf16x8 b = *(bf16x8*)&Vt[(dt*16 + fr)*200 + fc*64 + kc*32 + fq*8];
#pragma unroll
                for (int mt = 0; mt < 3; mt++)
                    O[mt][dt] = __builtin_amdgcn_mfma_f32_16x16x32_bf16(ap[mt], b, O[mt][dt], 0, 0, 0);
            }
        }
    }
    __bf16* obase = OT + ((size_t)(bn*8 + nh)) * SEQ * 64;
#pragma unroll
    for (int mt = 0; mt < 3; mt++)
#pragma unroll
        for (int reg = 0; reg < 4; reg++) {
            int e = 48*w + mt*16 + fq*4 + reg;
#pragma unroll
            for (int dt = 0; dt < 4; dt++)
                obase[(size_t)e*64 + dt*16 + fr] = (__bf16)O[mt][dt][reg];
        }
}

// ---------------- BatchNorm stats, two-stage (channel = flat % 512) ----------------
// stage 1: 256 blocks x 96 rows; named f32x4 accumulators (registers, no scratch);
// LDS reduce across 4 rowlanes; per-block partials (no atomics).
__global__ __launch_bounds__(256) void bn_stats1_k(const __bf16* __restrict__ x, float* __restrict__ part)
{
    __shared__ float red[3072];            // 3 rowlanes x (512 sum + 512 sq)
    const int col8 = threadIdx.x & 63;     // 8 channels per thread
    const int rl   = threadIdx.x >> 6;     // 0..3
    const size_t r0 = (size_t)blockIdx.x * 96;
    f32x4 sA = {0,0,0,0}, sB = {0,0,0,0}, qA = {0,0,0,0}, qB = {0,0,0,0};
    for (int r = rl; r < 96; r += 4) {
        bf16x8 v = *(const bf16x8*)&x[(r0 + r)*512 + col8*8];
        f32x4 lo = { (float)v[0], (float)v[1], (float)v[2], (float)v[3] };
        f32x4 hi = { (float)v[4], (float)v[5], (float)v[6], (float)v[7] };
        sA += lo; sB += hi;
        qA += lo*lo; qB += hi*hi;
    }
    if (rl > 0) {
        float* p = &red[(rl-1)*1024];
        *(f32x4*)&p[col8*8]       = sA;  *(f32x4*)&p[col8*8 + 4]       = sB;
        *(f32x4*)&p[512 + col8*8] = qA;  *(f32x4*)&p[512 + col8*8 + 4] = qB;
    }
    __syncthreads();
    if (rl == 0) {
#pragma unroll
        for (int k = 0; k < 3; k++) {
            float* p = &red[k*1024];
            sA += *(f32x4*)&p[col8*8];       sB += *(f32x4*)&p[col8*8 + 4];
            qA += *(f32x4*)&p[512 + col8*8]; qB += *(f32x4*)&p[512 + col8*8 + 4];
        }
        float* o = &part[(size_t)blockIdx.x * 1024];
        *(f32x4*)&o[col8*8]       = sA;  *(f32x4*)&o[col8*8 + 4]       = sB;
        *(f32x4*)&o[512 + col8*8] = qA;  *(f32x4*)&o[512 + col8*8 + 4] = qB;
    }
}

// stage 2: sum 256 partials per channel-stat, plain store
__global__ __launch_bounds__(256) void bn_stats2_k(const float* __restrict__ part, float* __restrict__ st)
{
    int c = blockIdx.x * 256 + threadIdx.x;   // grid 4 -> 1024
    float s0 = 0.f, s1 = 0.f, s2 = 0.f, s3 = 0.f;
    for (int b = 0; b < 256; b += 4) {
        s0 += part[(size_t)b*1024 + c];
        s1 += part[(size_t)(b+1)*1024 + c];
        s2 += part[(size_t)(b+2)*1024 + c];
        s3 += part[(size_t)(b+3)*1024 + c];
    }
    st[c] = (s0 + s1) + (s2 + s3);
}

__global__ void bn_coef_k(const float* __restrict__ st, const float* __restrict__ g,
                          const float* __restrict__ b, float* __restrict__ coef)
{
    int c = threadIdx.x;   // 512
    float mean = st[c] * (1.f/24576.f);
    float var  = st[512+c] * (1.f/24576.f) - mean*mean;
    float sc = rsqrtf(var + EPS) * g[c];
    coef[c] = sc;
    coef[512 + c] = b[c] - mean * sc;
}

__global__ __launch_bounds__(256) void bn_apply4_k(const float* __restrict__ x, const float* __restrict__ st,
    const float* __restrict__ g, const float* __restrict__ b, float* __restrict__ out)
{
    size_t i = (size_t)blockIdx.x * 256 + threadIdx.x;   // 12288 blocks
    int col4 = i & 127;
    f32x4 v = ((const f32x4*)x)[i];
    f32x4 sm = ((const f32x4*)st)[col4];
    f32x4 sq = ((const f32x4*)(st + 512))[col4];
    f32x4 o;
#pragma unroll
    for (int j = 0; j < 4; j++) {
        int c = col4*4 + j;
        float mean = sm[j] * (1.f/24576.f);
        float var  = sq[j] * (1.f/24576.f) - mean*mean;
        o[j] = (v[j] - mean) * rsqrtf(var + EPS) * g[c] + b[c];
    }
    ((f32x4*)out)[i] = o;
}

extern "C" void kernel_launch(void* const* d_in, const int* in_sizes, int n_in,
                              void* d_out, int out_size, void* d_ws, size_t ws_size,
                              hipStream_t stream)
{
    const float* src    = (const float*)d_in[0];
    const float* qk_w   = (const float*)d_in[1];
    const float* qk_b   = (const float*)d_in[2];
    const float* v_w    = (const float*)d_in[3];
    const float* v_b    = (const float*)d_in[4];
    const float* alpha  = (const float*)d_in[5];
    const float* g_pre1 = (const float*)d_in[6];
    const float* b_pre1 = (const float*)d_in[7];
    const float* g_pre2 = (const float*)d_in[8];
    const float* b_pre2 = (const float*)d_in[9];
    const float* ff1_w1 = (const float*)d_in[10];
    const float* ff1_b1 = (const float*)d_in[11];
    const float* ff1_w2 = (const float*)d_in[12];
    const float* ff1_b2 = (const float*)d_in[13];
    const float* ff2_w1 = (const float*)d_in[14];
    const float* ff2_b1 = (const float*)d_in[15];
    const float* ff2_w2 = (const float*)d_in[16];
    const float* ff2_b2 = (const float*)d_in[17];
    const float* g_attn = (const float*)d_in[18];
    const float* b_attn = (const float*)d_in[19];
    float* out = (float*)d_out;

    // ws layout (bf16 units) — ~187 MB total
    __bf16* wq   = (__bf16*)d_ws;                       //  524288
    __bf16* wv   = wq  + 524288;                        //  262144
    __bf16* w11  = wv  + 262144;                        // 1048576
    __bf16* w12  = w11 + 1048576;                       // 1048576
    __bf16* w21  = w12 + 1048576;                       // 1048576
    __bf16* w22  = w21 + 1048576;                       // 1048576
    __bf16* srcb  = w22 + 1048576;                      // 12582912
    __bf16* srcnb = srcb + (size_t)NTOK*512;            // 12582912
    __bf16* QKb   = srcnb + (size_t)NTOK*512;           // 25165824
    __bf16* Vb    = QKb + (size_t)NTOK*1024;            // 12582912
    __bf16* OHbf  = Vb + (size_t)NTOK*512;              // 12582912
    __bf16* o3bf  = OHbf + (size_t)NTOK*512;            // 12582912
    float*  stats = (float*)(o3bf + (size_t)NTOK*512);  // 3072 f32
    float*  coef0 = stats + 3072;                       // 1024 f32 (o3 BN)
    float*  coef1 = coef0 + 1024;                       // 1024 f32 (o2 BN)
    float*  part0 = coef1 + 1024;                       // 262144 f32 (1 MB)
    float*  part1 = part0 + 262144;                     // 262144 f32
    // FFN hidden (per 12288-row chunk) overlays the dead srcb..Vb span:
    __bf16* H1 = srcb;                                  // 12288 x 2048
    __bf16* H2 = H1 + (size_t)12288*2048;               // 12288 x 2048
    float *st0 = stats, *st1 = stats + 1024, *st2 = stats + 2048;

    hipMemsetAsync(st2, 0, 1024*sizeof(float), stream);

    // 0. one-time bf16 conversions
    cvt_k<<<512,  256, 0, stream>>>(qk_w,   wq);
    cvt_k<<<256,  256, 0, stream>>>(v_w,    wv);
    cvt_k<<<1024, 256, 0, stream>>>(ff1_w1, w11);
    cvt_k<<<1024, 256, 0, stream>>>(ff1_w2, w12);
    cvt_k<<<1024, 256, 0, stream>>>(ff2_w1, w21);
    cvt_k<<<1024, 256, 0, stream>>>(ff2_w2, w22);
    prep_k<<<NTOK/4, 256, 0, stream>>>(src, srcb, srcnb);

    // 1. projections
    gemm_k<false,false><<<dim3(8, 192), 256, 0, stream>>>(srcnb, wq, QKb, 1024, 512, qk_b, nullptr);
    gemm_k<false,false><<<dim3(4, 192), 256, 0, stream>>>(srcb,  wv, Vb,  512,  512, v_b,  nullptr);

    // 2. hidden-axis attention on UN-decayed q,k -> bf16
    hidden_attn_mfma_k<<<1024, 256, 0, stream>>>(QKb, Vb, OHbf);

    // 3. decay scan in place, then MFMA token attention -> bf16 o3
    decay_scan_k<<<512, 256, 0, stream>>>(QKb, alpha);
    token_attn_mfma_k<<<1024, 256, 0, stream>>>(QKb, Vb, o3bf);

    // 4. BN stats (two-stage, no atomics); both BN applies fold into W1 staging
    bn_stats1_k<<<256, 256, 0, stream>>>(o3bf, part0);      // out_tok -> pre2
    bn_stats1_k<<<256, 256, 0, stream>>>(OHbf, part1);      // out_hid -> pre1
    bn_stats2_k<<<4, 256, 0, stream>>>(part0, st0);
    bn_stats2_k<<<4, 256, 0, stream>>>(part1, st1);
    bn_coef_k<<<1, 512, 0, stream>>>(st0, g_pre2, b_pre2, coef0);
    bn_coef_k<<<1, 512, 0, stream>>>(st1, g_pre1, b_pre1, coef1);

    // 5. FFN in 2 chunks of 12288 rows; H1/H2 overlay the dead srcb..Vb span.
    //    Both W1 GEMMs apply their BN affine during A-staging;
    //    gemm2 fuses both W2 matmuls + biases + residual + final-BN stats.
    for (int ch = 0; ch < 2; ch++) {
        size_t off = (size_t)ch * 12288 * 512;
        gemm_k<true,true><<<dim3(16, 96), 256, 0, stream>>>(o3bf + off, w11, H1, 2048, 512, ff1_b1, coef0);
        gemm_k<true,true><<<dim3(16, 96), 256, 0, stream>>>(OHbf + off, w21, H2, 2048, 512, ff2_b1, coef1);
        gemm2_k<<<dim3(4, 96), 256, 0, stream>>>(H1, H2, w12, w22, out + off,
                                                 ff1_b2, ff2_b2, src + off, st2);
    }

    // 6. final BN (in place on d_out)
    bn_apply4_k<<<12288, 256, 0, stream>>>(out, st2, g_attn, b_attn, out);
}

// Round 7
// 708.600 us; speedup vs baseline: 1.4356x; 1.1104x over previous
//
#include <hip/hip_runtime.h>
#include <math.h>

#define SEQ 192
#define NTOK 24576      // 128*192
#define EPS 1e-5f

typedef __bf16 bf16x8 __attribute__((ext_vector_type(8)));
typedef __bf16 bf16x4 __attribute__((ext_vector_type(4)));
typedef float  f32x4  __attribute__((ext_vector_type(4)));

__device__ __forceinline__ void load_lds16(const __bf16* g, __bf16* l) {
    __builtin_amdgcn_global_load_lds(
        (const __attribute__((address_space(1))) uint32_t*)g,
        (__attribute__((address_space(3))) uint32_t*)l, 16, 0, 0);
}

// tanh-form GELU via sigmoid: x*sigmoid(1.5958*(x+0.044715 x^3))
__device__ __forceinline__ float gelu_f(float x) {
    float z = 1.5957691216057308f * x * fmaf(0.044715f, x*x, 1.f);
    float e = __expf(-z);
    return x * __builtin_amdgcn_rcpf(1.f + e);
}

// ---------------- fused f32 -> bf16 weight convert (dst contiguous) ----------------
__global__ __launch_bounds__(256) void cvtall_k(
    const float* __restrict__ s0, const float* __restrict__ s1, const float* __restrict__ s2,
    const float* __restrict__ s3, const float* __restrict__ s4, const float* __restrict__ s5,
    __bf16* __restrict__ dst)
{
    int i = blockIdx.x * 256 + threadIdx.x;   // f32x4 units; grid 4864 -> 1245184 units
    int f = i * 4;
    const float* s; int off;
    if      (f <  524288) { s = s0; off = 0;       }
    else if (f <  786432) { s = s1; off = 524288;  }
    else if (f < 1835008) { s = s2; off = 786432;  }
    else if (f < 2883584) { s = s3; off = 1835008; }
    else if (f < 3932160) { s = s4; off = 2883584; }
    else                  { s = s5; off = 3932160; }
    f32x4 v = *(const f32x4*)&s[f - off];
    bf16x4 o;
    o[0]=(__bf16)v[0]; o[1]=(__bf16)v[1]; o[2]=(__bf16)v[2]; o[3]=(__bf16)v[3];
    ((bf16x4*)dst)[i] = o;
}

// ---------------- prep: src -> bf16 raw + bf16 L2-normalized ----------------
__global__ __launch_bounds__(256) void prep_k(const float* __restrict__ src,
    __bf16* __restrict__ srcb, __bf16* __restrict__ srcnb)
{
    int w = threadIdx.x >> 6, lane = threadIdx.x & 63;
    size_t token = blockIdx.x * 4 + w;
    const float* p = src + token * 512 + lane * 8;
    f32x4 a0 = *(const f32x4*)p;
    f32x4 a1 = *(const f32x4*)(p + 4);
    float s = a0[0]*a0[0]+a0[1]*a0[1]+a0[2]*a0[2]+a0[3]*a0[3]
            + a1[0]*a1[0]+a1[1]*a1[1]+a1[2]*a1[2]+a1[3]*a1[3];
#pragma unroll
    for (int off = 32; off; off >>= 1) s += __shfl_xor(s, off);
    float rs = rsqrtf(s);
    bf16x8 vb, vn;
#pragma unroll
    for (int q = 0; q < 4; q++) {
        vb[q]   = (__bf16)a0[q];      vn[q]   = (__bf16)(a0[q]*rs);
        vb[q+4] = (__bf16)a1[q];      vn[q+4] = (__bf16)(a1[q]*rs);
    }
    *(bf16x8*)&srcb[token*512 + lane*8]  = vb;
    *(bf16x8*)&srcnb[token*512 + lane*8] = vn;
}

// ---------------- bf16 MFMA NT GEMM, BK=64, XOR-swizzled LDS, bf16 out ----------------
// 128x128 tile; grid-y (m-tiles) XCD-grouped so same-m blocks share one L2.
template<bool AFFINE, bool GELU>
__global__ __launch_bounds__(256) void gemm_k(
    const __bf16* __restrict__ A, const __bf16* __restrict__ B, __bf16* __restrict__ C,
    int N, int K, const float* __restrict__ bias, const float* __restrict__ coef)
{
    __shared__ __bf16 As[8192];   // [128][64], seg XOR-swizzled
    __shared__ __bf16 Bs[8192];
    const int tid = threadIdx.x, lane = tid & 63, w = tid >> 6;
    const int wr = w >> 1, wc = w & 1;
    // XCD swizzle: all gridDim.x n-tiles of one m-tile stay on one XCD (gridDim.y % 8 == 0)
    const int b = blockIdx.y * gridDim.x + blockIdx.x;
    const int xcd = b & 7, bi = b >> 3;
    const int ypx = gridDim.y >> 3;
    const int m0 = (xcd * ypx + bi / gridDim.x) * 128;
    const int n0 = (bi % gridDim.x) * 128;
    const int fr = lane & 15, fq = lane >> 4;
    const int grow = 8*w + (lane >> 3);
    const int gcol = ((lane & 7) ^ (lane >> 3)) * 8;
    const __bf16* gB = B + (size_t)(n0 + grow) * K + gcol;
    const __bf16* gA = A + (size_t)(m0 + grow) * K + gcol;
    __bf16* ldsA = As + 8*w*64 + lane*8;
    __bf16* ldsB = Bs + 8*w*64 + lane*8;

    f32x4 acc[4][4];
#pragma unroll
    for (int i = 0; i < 4; i++)
#pragma unroll
        for (int j = 0; j < 4; j++) acc[i][j] = (f32x4){0.f,0.f,0.f,0.f};

    for (int k0 = 0; k0 < K; k0 += 64) {
        if (!AFFINE) {
#pragma unroll
            for (int i = 0; i < 4; i++)
                load_lds16(gA + k0 + (size_t)(32*i)*K, ldsA + i*2048);
        } else {
            const int r = tid >> 3, cseg = tid & 7;
            const float* scp = coef + k0 + cseg*8;
            const float* shp = coef + 512 + k0 + cseg*8;
            f32x4 sc0 = *(const f32x4*)scp, sc1 = *(const f32x4*)(scp+4);
            f32x4 sh0 = *(const f32x4*)shp, sh1 = *(const f32x4*)(shp+4);
#pragma unroll
            for (int i = 0; i < 4; i++) {
                int row = 32*i + r;
                bf16x8 a = *(const bf16x8*)&A[(size_t)(m0+row)*512 + k0 + cseg*8];
                bf16x8 v;
#pragma unroll
                for (int q = 0; q < 4; q++) {
                    v[q]   = (__bf16)fmaf((float)a[q],   sc0[q], sh0[q]);
                    v[q+4] = (__bf16)fmaf((float)a[q+4], sc1[q], sh1[q]);
                }
                *(bf16x8*)&As[row*64 + ((cseg ^ (r & 7)) * 8)] = v;
            }
        }
#pragma unroll
        for (int i = 0; i < 4; i++)
            load_lds16(gB + k0 + (size_t)(32*i)*K, ldsB + i*2048);
        __syncthreads();
#pragma unroll
        for (int kk = 0; kk < 2; kk++) {
            bf16x8 af[4], bfv[4];
#pragma unroll
            for (int i = 0; i < 4; i++)
                af[i] = *(bf16x8*)&As[(wr*64 + i*16 + fr)*64 + (((kk*4+fq) ^ (fr&7))*8)];
#pragma unroll
            for (int j = 0; j < 4; j++)
                bfv[j] = *(bf16x8*)&Bs[(wc*64 + j*16 + fr)*64 + (((kk*4+fq) ^ (fr&7))*8)];
#pragma unroll
            for (int i = 0; i < 4; i++)
#pragma unroll
                for (int j = 0; j < 4; j++)
                    acc[i][j] = __builtin_amdgcn_mfma_f32_16x16x32_bf16(af[i], bfv[j], acc[i][j], 0, 0, 0);
        }
        __syncthreads();
    }
    const int r4 = lane >> 4, cc = lane & 15;
#pragma unroll
    for (int i = 0; i < 4; i++) {
#pragma unroll
        for (int r = 0; r < 4; r++) {
            int m = m0 + wr*64 + i*16 + r4*4 + r;
#pragma unroll
            for (int j = 0; j < 4; j++) {
                int n = n0 + wc*64 + j*16 + cc;
                float v = acc[i][j][r] + bias[n];
                if (GELU) v = gelu_f(v);
                C[(size_t)m * N + n] = (__bf16)v;
            }
        }
    }
}

// ---------------- dual-source W2 GEMM: out = H1*B1^T + H2*B2^T + b1 + b2 + resid ----------------
// 64x128 tile, 1D grid 768/chunk, XCD-grouped (4 n-tiles of one m-tile on one XCD).
// K = 2048 per source; N = 512; f32 out + final-BN stats via atomics.
__global__ __launch_bounds__(256) void gemm2_k(
    const __bf16* __restrict__ A1, const __bf16* __restrict__ A2,
    const __bf16* __restrict__ B1, const __bf16* __restrict__ B2,
    float* __restrict__ C, const float* __restrict__ b1, const float* __restrict__ b2,
    const float* __restrict__ resid, float* __restrict__ st)
{
    __shared__ __bf16 As[4096];   // 64 x 64
    __shared__ __bf16 Bs[8192];   // 128 x 64
    const int tid = threadIdx.x, lane = tid & 63, w = tid >> 6;
    const int wr = w >> 1, wc = w & 1;
    const int vb = blockIdx.x;                  // 768 = 8 xcd * 24 m * 4 n
    const int xcd = vb & 7, k2 = vb >> 3;
    const int m0 = (xcd*24 + (k2 >> 2)) * 64;
    const int n0 = (k2 & 3) * 128;
    const int fr = lane & 15, fq = lane >> 4;
    const int grow = 8*w + (lane >> 3);
    const int gcol = ((lane & 7) ^ (lane >> 3)) * 8;
    const int K = 2048;
    __bf16* ldsA = As + 8*w*64 + lane*8;
    __bf16* ldsB = Bs + 8*w*64 + lane*8;

    f32x4 acc[2][4];
#pragma unroll
    for (int i = 0; i < 2; i++)
#pragma unroll
        for (int j = 0; j < 4; j++) acc[i][j] = (f32x4){0.f,0.f,0.f,0.f};

#pragma unroll 1
    for (int half = 0; half < 2; half++) {
        const __bf16* gA = (half ? A2 : A1) + (size_t)(m0 + grow) * K + gcol;
        const __bf16* gB = (half ? B2 : B1) + (size_t)(n0 + grow) * K + gcol;
        for (int k0 = 0; k0 < K; k0 += 64) {
            load_lds16(gA + k0,                 ldsA);
            load_lds16(gA + k0 + (size_t)32*K,  ldsA + 2048);
#pragma unroll
            for (int i = 0; i < 4; i++)
                load_lds16(gB + k0 + (size_t)(32*i)*K, ldsB + i*2048);
            __syncthreads();
#pragma unroll
            for (int kk = 0; kk < 2; kk++) {
                bf16x8 af[2], bfv[4];
#pragma unroll
                for (int i = 0; i < 2; i++)
                    af[i] = *(bf16x8*)&As[(wr*32 + i*16 + fr)*64 + (((kk*4+fq) ^ (fr&7))*8)];
#pragma unroll
                for (int j = 0; j < 4; j++)
                    bfv[j] = *(bf16x8*)&Bs[(wc*64 + j*16 + fr)*64 + (((kk*4+fq) ^ (fr&7))*8)];
#pragma unroll
                for (int i = 0; i < 2; i++)
#pragma unroll
                    for (int j = 0; j < 4; j++)
                        acc[i][j] = __builtin_amdgcn_mfma_f32_16x16x32_bf16(af[i], bfv[j], acc[i][j], 0, 0, 0);
            }
            __syncthreads();
        }
    }
    const int r4 = lane >> 4, cc = lane & 15;
    float cs[4] = {0,0,0,0}, cq[4] = {0,0,0,0};
#pragma unroll
    for (int i = 0; i < 2; i++) {
#pragma unroll
        for (int r = 0; r < 4; r++) {
            int m = m0 + wr*32 + i*16 + r4*4 + r;
#pragma unroll
            for (int j = 0; j < 4; j++) {
                int n = n0 + wc*64 + j*16 + cc;
                size_t idx = (size_t)m * 512 + n;
                float v = acc[i][j][r] + b1[n] + b2[n] + resid[idx];
                C[idx] = v;
                cs[j] += v; cq[j] = fmaf(v, v, cq[j]);
            }
        }
    }
#pragma unroll
    for (int j = 0; j < 4; j++) {
        cs[j] += __shfl_xor(cs[j], 16); cs[j] += __shfl_xor(cs[j], 32);
        cq[j] += __shfl_xor(cq[j], 16); cq[j] += __shfl_xor(cq[j], 32);
    }
    if (r4 == 0) {
#pragma unroll
        for (int j = 0; j < 4; j++) {
            int n = n0 + wc*64 + j*16 + cc;
            atomicAdd(&st[n], cs[j]);
            atomicAdd(&st[512 + n], cq[j]);
        }
    }
}

// ---------------- exponential-decay causal scan (replaces FFT), in place, bf16x4 ----------------
__global__ __launch_bounds__(256) void decay_scan_k(__bf16* __restrict__ QKb, const float* __restrict__ alpha)
{
    int g = blockIdx.x * 256 + threadIdx.x;   // 32768 threads, 4 channels each
    int bn = g >> 8, e4 = (g & 255) * 4;
    int ai = e4 & 63;
    f32x4 a, rr;
#pragma unroll
    for (int j = 0; j < 4; j++) { float av = 1.f/(1.f + __expf(-alpha[ai + j])); a[j] = av; rr[j] = 1.f - av; }
    __bf16* p = QKb + (size_t)bn * SEQ * 1024 + e4;
    f32x4 P = {0,0,0,0}, pw = {1,1,1,1};
    for (int t = 0; t < SEQ; t++) {
        bf16x4 v = *(bf16x4*)&p[(size_t)t*1024];
        f32x4 vf = { (float)v[0], (float)v[1], (float)v[2], (float)v[3] };
        P += pw * vf;
        bf16x4 o;
#pragma unroll
        for (int j = 0; j < 4; j++) o[j] = (__bf16)P[j];
        *(bf16x4*)&p[(size_t)t*1024] = o;
        pw *= rr;
    }
    f32x4 f = a;
    for (int t = SEQ-1; t >= 0; t--) {
        bf16x4 v = *(bf16x4*)&p[(size_t)t*1024];
        bf16x4 o;
#pragma unroll
        for (int j = 0; j < 4; j++) o[j] = (__bf16)((float)v[j] * f[j]);
        *(bf16x4*)&p[(size_t)t*1024] = o;
        f *= rr;
    }
}

// ---------------- hidden-axis attention, MFMA. block=(bn,nh), 256 thr, bf16 out ----------------
__global__ __launch_bounds__(256) void hidden_attn_mfma_k(
    const __bf16* __restrict__ QKb, const __bf16* __restrict__ Vb, __bf16* __restrict__ OHb)
{
    __shared__ __bf16 smem[25600];
    __bf16* Qt = smem;             // 64 x 200 (phase 1)  [e][t]
    __bf16* Kt = smem + 12800;     // 64 x 200            [f][t]
    __bf16* Ps = smem;             // 64 x 72  (phase 2)  [e][f]
    __bf16* Vs = smem + 4608;      // 192 x 72            [t][f]
    const int bn = blockIdx.x >> 3, nh = blockIdx.x & 7;
    const int tid = threadIdx.x, lane = tid & 63, w = tid >> 6;
    const int fr = lane & 15, fq = lane >> 4;
    const size_t rowbase = (size_t)bn * SEQ;

    // transpose-stage q^T,k^T: per task one column-of-8 (8 coalesced reads + 1 b128 write)
#pragma unroll
    for (int it = 0; it < 12; it++) {
        int tk = tid + (it % 6) * 256;          // 0..1535
        int j = tk & 63, tg = tk >> 6;          // tg 0..23
        const __bf16* gsrc = QKb + (rowbase + tg*8)*1024 + nh*64 + j + (it >= 6 ? 512 : 0);
        bf16x8 v;
#pragma unroll
        for (int u = 0; u < 8; u++) v[u] = gsrc[(size_t)u*1024];
        __bf16* dst = (it >= 6 ? Kt : Qt) + j*200 + tg*8;
        *(bf16x8*)dst = v;
    }
    __syncthreads();

    f32x4 acc[4];
#pragma unroll
    for (int i = 0; i < 4; i++) acc[i] = (f32x4){0.f,0.f,0.f,0.f};
#pragma unroll
    for (int kc = 0; kc < 6; kc++) {
        bf16x8 a = *(bf16x8*)&Qt[(w*16 + fr)*200 + kc*32 + fq*8];
#pragma unroll
        for (int nt = 0; nt < 4; nt++) {
            bf16x8 b = *(bf16x8*)&Kt[(nt*16 + fr)*200 + kc*32 + fq*8];
            acc[nt] = __builtin_amdgcn_mfma_f32_16x16x32_bf16(a, b, acc[nt], 0, 0, 0);
        }
    }
    const float sc = 13.856406460551018f;   // sqrt(192)
    float pn[4][4];
#pragma unroll
    for (int reg = 0; reg < 4; reg++) {
        float m = -1e30f;
#pragma unroll
        for (int nt = 0; nt < 4; nt++) { acc[nt][reg] *= sc; m = fmaxf(m, acc[nt][reg]); }
#pragma unroll
        for (int off = 1; off < 16; off <<= 1) m = fmaxf(m, __shfl_xor(m, off));
        float l = 0.f;
#pragma unroll
        for (int nt = 0; nt < 4; nt++) { pn[nt][reg] = __expf(acc[nt][reg] - m); l += pn[nt][reg]; }
#pragma unroll
        for (int off = 1; off < 16; off <<= 1) l += __shfl_xor(l, off);
        float inv = 1.f / l;
#pragma unroll
        for (int nt = 0; nt < 4; nt++) pn[nt][reg] *= inv;
    }
    __syncthreads();                                   // Qt/Kt dead
#pragma unroll
    for (int nt = 0; nt < 4; nt++)
#pragma unroll
        for (int reg = 0; reg < 4; reg++)
            Ps[(w*16 + fq*4 + reg)*72 + nt*16 + fr] = (__bf16)pn[nt][reg];
    for (int i = tid; i < 1536; i += 256) {            // stage V natural
        int t = i >> 3, s = i & 7;
        *(bf16x8*)&Vs[t*72 + s*8] = *(const bf16x8*)&Vb[(rowbase+t)*512 + nh*64 + s*8];
    }
    __syncthreads();

    f32x4 o[3][4];
#pragma unroll
    for (int i = 0; i < 3; i++)
#pragma unroll
        for (int j = 0; j < 4; j++) o[i][j] = (f32x4){0.f,0.f,0.f,0.f};
#pragma unroll
    for (int kc = 0; kc < 2; kc++) {
        bf16x8 av[3];
#pragma unroll
        for (int mt = 0; mt < 3; mt++)
            av[mt] = *(bf16x8*)&Vs[(48*w + mt*16 + fr)*72 + kc*32 + fq*8];
#pragma unroll
        for (int nt = 0; nt < 4; nt++) {
            bf16x8 b = *(bf16x8*)&Ps[(nt*16 + fr)*72 + kc*32 + fq*8];
#pragma unroll
            for (int mt = 0; mt < 3; mt++)
                o[mt][nt] = __builtin_amdgcn_mfma_f32_16x16x32_bf16(av[mt], b, o[mt][nt], 0, 0, 0);
        }
    }
    __bf16* obase = OHb + ((size_t)(bn*8 + nh)) * SEQ * 64;
#pragma unroll
    for (int mt = 0; mt < 3; mt++)
#pragma unroll
        for (int reg = 0; reg < 4; reg++) {
            int t = 48*w + mt*16 + fq*4 + reg;
#pragma unroll
            for (int nt = 0; nt < 4; nt++)
                obase[(size_t)t*64 + nt*16 + fr] = (__bf16)o[mt][nt][reg];
        }
}

// ---------------- token-axis attention, MFMA. block=(bn,nh), 256 thr, bf16 out ----------------
__global__ __launch_bounds__(256) void token_attn_mfma_k(
    const __bf16* __restrict__ QKb, const __bf16* __restrict__ Vb, __bf16* __restrict__ OT)
{
    __shared__ __bf16 smem[27648];
    __bf16* Qs = smem;              // 192 x 72 (phase A) [e][d]
    __bf16* Ks = smem + 13824;      // 192 x 72           [f][d]
    __bf16* Vt = smem;              // 64 x 200 (phase B) [d][f]
    __bf16* Pw = smem + 12800;      // 4 waves x (48 x 72)
    const int bn = blockIdx.x >> 3, nh = blockIdx.x & 7;
    const int tid = threadIdx.x, lane = tid & 63, w = tid >> 6;
    const int fr = lane & 15, fq = lane >> 4;
    const size_t rowbase = (size_t)bn * SEQ;

    for (int i = tid; i < 1536; i += 256) {
        int t = i >> 3, s = i & 7;
        const __bf16* g = QKb + (rowbase + t)*1024 + nh*64;
        *(bf16x8*)&Qs[t*72 + s*8] = *(const bf16x8*)&g[s*8];
        *(bf16x8*)&Ks[t*72 + s*8] = *(const bf16x8*)&g[512 + s*8];
    }
    __syncthreads();

    f32x4 S[3][12];
#pragma unroll
    for (int i = 0; i < 3; i++)
#pragma unroll
        for (int j = 0; j < 12; j++) S[i][j] = (f32x4){0.f,0.f,0.f,0.f};
#pragma unroll
    for (int kc = 0; kc < 2; kc++) {
        bf16x8 aq[3];
#pragma unroll
        for (int mt = 0; mt < 3; mt++)
            aq[mt] = *(bf16x8*)&Qs[(48*w + mt*16 + fr)*72 + kc*32 + fq*8];
#pragma unroll
        for (int nt = 0; nt < 12; nt++) {
            bf16x8 b = *(bf16x8*)&Ks[(nt*16 + fr)*72 + kc*32 + fq*8];
#pragma unroll
            for (int mt = 0; mt < 3; mt++)
                S[mt][nt] = __builtin_amdgcn_mfma_f32_16x16x32_bf16(aq[mt], b, S[mt][nt], 0, 0, 0);
        }
    }
#pragma unroll
    for (int mt = 0; mt < 3; mt++)
#pragma unroll
        for (int reg = 0; reg < 4; reg++) {
            float m = -1e30f;
#pragma unroll
            for (int nt = 0; nt < 12; nt++) { S[mt][nt][reg] *= 8.f; m = fmaxf(m, S[mt][nt][reg]); }
#pragma unroll
            for (int off = 1; off < 16; off <<= 1) m = fmaxf(m, __shfl_xor(m, off));
            float l = 0.f;
#pragma unroll
            for (int nt = 0; nt < 12; nt++) { S[mt][nt][reg] = __expf(S[mt][nt][reg] - m); l += S[mt][nt][reg]; }
#pragma unroll
            for (int off = 1; off < 16; off <<= 1) l += __shfl_xor(l, off);
            float inv = 1.f / l;
#pragma unroll
            for (int nt = 0; nt < 12; nt++) S[mt][nt][reg] *= inv;
        }
    __syncthreads();                                   // Qs/Ks dead
    // transpose-stage V^T: per task one column-of-8
#pragma unroll
    for (int it = 0; it < 6; it++) {
        int tk = tid + it * 256;                // 0..1535
        int d = tk & 63, tg = tk >> 6;
        const __bf16* gsrc = Vb + (rowbase + tg*8)*512 + nh*64 + d;
        bf16x8 v;
#pragma unroll
        for (int u = 0; u < 8; u++) v[u] = gsrc[(size_t)u*512];
        *(bf16x8*)&Vt[d*200 + tg*8] = v;
    }
    __syncthreads();

    f32x4 O[3][4];
#pragma unroll
    for (int i = 0; i < 3; i++)
#pragma unroll
        for (int j = 0; j < 4; j++) O[i][j] = (f32x4){0.f,0.f,0.f,0.f};
    __bf16* myP = Pw + w*3456;
#pragma unroll
    for (int fc = 0; fc < 3; fc++) {
#pragma unroll
        for (int mt = 0; mt < 3; mt++)
#pragma unroll
            for (int j = 0; j < 4; j++)
#pragma unroll
                for (int reg = 0; reg < 4; reg++)
                    myP[(mt*16 + fq*4 + reg)*72 + j*16 + fr] = (__bf16)S[mt][fc*4 + j][reg];
        // per-wave LDS region; DS ops are in-order per wave -> no barrier needed
#pragma unroll
        for (int kc = 0; kc < 2; kc++) {
            bf16x8 ap[3];
#pragma unroll
            for (int mt = 0; mt < 3; mt++)
                ap[mt] = *(bf16x8*)&myP[(mt*16 + fr)*72 + kc*32 + fq*8];
#pragma unroll
            for (int dt = 0; dt < 4; dt++) {
                bf16x8 b = *(bf16x8*)&Vt[(dt*16 + fr)*200 + fc*64 + kc*32 + fq*8];
#pragma unroll
                for (int mt = 0; mt < 3; mt++)
                    O[mt][dt] = __builtin_amdgcn_mfma_f32_16x16x32_bf16(ap[mt], b, O[mt][dt], 0, 0, 0);
            }
        }
    }
    __bf16* obase = OT + ((size_t)(bn*8 + nh)) * SEQ * 64;
#pragma unroll
    for (int mt = 0; mt < 3; mt++)
#pragma unroll
        for (int reg = 0; reg < 4; reg++) {
            int e = 48*w + mt*16 + fq*4 + reg;
#pragma unroll
            for (int dt = 0; dt < 4; dt++)
                obase[(size_t)e*64 + dt*16 + fr] = (__bf16)O[mt][dt][reg];
        }
}

// ---------------- BatchNorm stats, two-stage (channel = flat % 512) ----------------
__global__ __launch_bounds__(256) void bn_stats1_k(const __bf16* __restrict__ x, float* __restrict__ part)
{
    __shared__ float red[3072];            // 3 rowlanes x (512 sum + 512 sq)
    const int col8 = threadIdx.x & 63;     // 8 channels per thread
    const int rl   = threadIdx.x >> 6;     // 0..3
    const size_t r0 = (size_t)blockIdx.x * 96;
    f32x4 sA = {0,0,0,0}, sB = {0,0,0,0}, qA = {0,0,0,0}, qB = {0,0,0,0};
    for (int r = rl; r < 96; r += 4) {
        bf16x8 v = *(const bf16x8*)&x[(r0 + r)*512 + col8*8];
        f32x4 lo = { (float)v[0], (float)v[1], (float)v[2], (float)v[3] };
        f32x4 hi = { (float)v[4], (float)v[5], (float)v[6], (float)v[7] };
        sA += lo; sB += hi;
        qA += lo*lo; qB += hi*hi;
    }
    if (rl > 0) {
        float* p = &red[(rl-1)*1024];
        *(f32x4*)&p[col8*8]       = sA;  *(f32x4*)&p[col8*8 + 4]       = sB;
        *(f32x4*)&p[512 + col8*8] = qA;  *(f32x4*)&p[512 + col8*8 + 4] = qB;
    }
    __syncthreads();
    if (rl == 0) {
#pragma unroll
        for (int k = 0; k < 3; k++) {
            float* p = &red[k*1024];
            sA += *(f32x4*)&p[col8*8];       sB += *(f32x4*)&p[col8*8 + 4];
            qA += *(f32x4*)&p[512 + col8*8]; qB += *(f32x4*)&p[512 + col8*8 + 4];
        }
        float* o = &part[(size_t)blockIdx.x * 1024];
        *(f32x4*)&o[col8*8]       = sA;  *(f32x4*)&o[col8*8 + 4]       = sB;
        *(f32x4*)&o[512 + col8*8] = qA;  *(f32x4*)&o[512 + col8*8 + 4] = qB;
    }
}

__global__ __launch_bounds__(256) void bn_stats2_k(const float* __restrict__ part, float* __restrict__ st)
{
    int c = blockIdx.x * 256 + threadIdx.x;   // grid 4 -> 1024
    float s0 = 0.f, s1 = 0.f, s2 = 0.f, s3 = 0.f;
    for (int b = 0; b < 256; b += 4) {
        s0 += part[(size_t)b*1024 + c];
        s1 += part[(size_t)(b+1)*1024 + c];
        s2 += part[(size_t)(b+2)*1024 + c];
        s3 += part[(size_t)(b+3)*1024 + c];
    }
    st[c] = (s0 + s1) + (s2 + s3);
}

__global__ void bn_coef_k(const float* __restrict__ st, const float* __restrict__ g,
                          const float* __restrict__ b, float* __restrict__ coef)
{
    int c = threadIdx.x;   // 512
    float mean = st[c] * (1.f/24576.f);
    float var  = st[512+c] * (1.f/24576.f) - mean*mean;
    float sc = rsqrtf(var + EPS) * g[c];
    coef[c] = sc;
    coef[512 + c] = b[c] - mean * sc;
}

__global__ __launch_bounds__(256) void bn_apply4_k(const float* __restrict__ x, const float* __restrict__ st,
    const float* __restrict__ g, const float* __restrict__ b, float* __restrict__ out)
{
    size_t i = (size_t)blockIdx.x * 256 + threadIdx.x;   // 12288 blocks
    int col4 = i & 127;
    f32x4 v = ((const f32x4*)x)[i];
    f32x4 sm = ((const f32x4*)st)[col4];
    f32x4 sq = ((const f32x4*)(st + 512))[col4];
    f32x4 o;
#pragma unroll
    for (int j = 0; j < 4; j++) {
        int c = col4*4 + j;
        float mean = sm[j] * (1.f/24576.f);
        float var  = sq[j] * (1.f/24576.f) - mean*mean;
        o[j] = (v[j] - mean) * rsqrtf(var + EPS) * g[c] + b[c];
    }
    ((f32x4*)out)[i] = o;
}

extern "C" void kernel_launch(void* const* d_in, const int* in_sizes, int n_in,
                              void* d_out, int out_size, void* d_ws, size_t ws_size,
                              hipStream_t stream)
{
    const float* src    = (const float*)d_in[0];
    const float* qk_w   = (const float*)d_in[1];
    const float* qk_b   = (const float*)d_in[2];
    const float* v_w    = (const float*)d_in[3];
    const float* v_b    = (const float*)d_in[4];
    const float* alpha  = (const float*)d_in[5];
    const float* g_pre1 = (const float*)d_in[6];
    const float* b_pre1 = (const float*)d_in[7];
    const float* g_pre2 = (const float*)d_in[8];
    const float* b_pre2 = (const float*)d_in[9];
    const float* ff1_w1 = (const float*)d_in[10];
    const float* ff1_b1 = (const float*)d_in[11];
    const float* ff1_w2 = (const float*)d_in[12];
    const float* ff1_b2 = (const float*)d_in[13];
    const float* ff2_w1 = (const float*)d_in[14];
    const float* ff2_b1 = (const float*)d_in[15];
    const float* ff2_w2 = (const float*)d_in[16];
    const float* ff2_b2 = (const float*)d_in[17];
    const float* g_attn = (const float*)d_in[18];
    const float* b_attn = (const float*)d_in[19];
    float* out = (float*)d_out;

    // ws layout (bf16 units) — ~187 MB total
    __bf16* wq   = (__bf16*)d_ws;                       //  524288
    __bf16* wv   = wq  + 524288;                        //  262144
    __bf16* w11  = wv  + 262144;                        // 1048576
    __bf16* w12  = w11 + 1048576;                       // 1048576
    __bf16* w21  = w12 + 1048576;                       // 1048576
    __bf16* w22  = w21 + 1048576;                       // 1048576
    __bf16* srcb  = w22 + 1048576;                      // 12582912
    __bf16* srcnb = srcb + (size_t)NTOK*512;            // 12582912
    __bf16* QKb   = srcnb + (size_t)NTOK*512;           // 25165824
    __bf16* Vb    = QKb + (size_t)NTOK*1024;            // 12582912
    __bf16* OHbf  = Vb + (size_t)NTOK*512;              // 12582912
    __bf16* o3bf  = OHbf + (size_t)NTOK*512;            // 12582912
    float*  stats = (float*)(o3bf + (size_t)NTOK*512);  // 3072 f32
    float*  coef0 = stats + 3072;                       // 1024 f32 (o3 BN)
    float*  coef1 = coef0 + 1024;                       // 1024 f32 (o2 BN)
    float*  part0 = coef1 + 1024;                       // 262144 f32 (1 MB)
    float*  part1 = part0 + 262144;                     // 262144 f32
    // FFN hidden (per 12288-row chunk) overlays the dead srcb..Vb span:
    __bf16* H1 = srcb;                                  // 12288 x 2048
    __bf16* H2 = H1 + (size_t)12288*2048;               // 12288 x 2048
    float *st0 = stats, *st1 = stats + 1024, *st2 = stats + 2048;

    hipMemsetAsync(st2, 0, 1024*sizeof(float), stream);

    // 0. one-time bf16 conversions (weights contiguous in ws -> one kernel)
    cvtall_k<<<4864, 256, 0, stream>>>(qk_w, v_w, ff1_w1, ff1_w2, ff2_w1, ff2_w2, wq);
    prep_k<<<NTOK/4, 256, 0, stream>>>(src, srcb, srcnb);

    // 1. projections
    gemm_k<false,false><<<dim3(8, 192), 256, 0, stream>>>(srcnb, wq, QKb, 1024, 512, qk_b, nullptr);
    gemm_k<false,false><<<dim3(4, 192), 256, 0, stream>>>(srcb,  wv, Vb,  512,  512, v_b,  nullptr);

    // 2. hidden-axis attention on UN-decayed q,k -> bf16
    hidden_attn_mfma_k<<<1024, 256, 0, stream>>>(QKb, Vb, OHbf);

    // 3. decay scan in place, then MFMA token attention -> bf16 o3
    decay_scan_k<<<128, 256, 0, stream>>>(QKb, alpha);
    token_attn_mfma_k<<<1024, 256, 0, stream>>>(QKb, Vb, o3bf);

    // 4. BN stats (two-stage, no atomics); both BN applies fold into W1 staging
    bn_stats1_k<<<256, 256, 0, stream>>>(o3bf, part0);      // out_tok -> pre2
    bn_stats1_k<<<256, 256, 0, stream>>>(OHbf, part1);      // out_hid -> pre1
    bn_stats2_k<<<4, 256, 0, stream>>>(part0, st0);
    bn_stats2_k<<<4, 256, 0, stream>>>(part1, st1);
    bn_coef_k<<<1, 512, 0, stream>>>(st0, g_pre2, b_pre2, coef0);
    bn_coef_k<<<1, 512, 0, stream>>>(st1, g_pre1, b_pre1, coef1);

    // 5. FFN in 2 chunks of 12288 rows; H1/H2 overlay the dead srcb..Vb span.
    //    W1 GEMMs apply BN affine during A-staging; gemm2 (64x128 tiles, XCD-
    //    swizzled, 768 blocks) fuses both W2 matmuls + biases + residual + stats.
    for (int ch = 0; ch < 2; ch++) {
        size_t off = (size_t)ch * 12288 * 512;
        gemm_k<true,true><<<dim3(16, 96), 256, 0, stream>>>(o3bf + off, w11, H1, 2048, 512, ff1_b1, coef0);
        gemm_k<true,true><<<dim3(16, 96), 256, 0, stream>>>(OHbf + off, w21, H2, 2048, 512, ff2_b1, coef1);
        gemm2_k<<<768, 256, 0, stream>>>(H1, H2, w12, w22, out + off,
                                         ff1_b2, ff2_b2, src + off, st2);
    }

    // 6. final BN (in place on d_out)
    bn_apply4_k<<<12288, 256, 0, stream>>>(out, st2, g_attn, b_attn, out);
}